// Round 6
// baseline (200.744 us; speedup 1.0000x reference)
//
#include <hip/hip_runtime.h>
#include <hip/hip_bf16.h>
#include <stdint.h>

// B=8, N=1024, D=1024.  out = relu(adj @ (y@W) / adj_sumrow + b + x)
// R9: R8 geometry (BM=256 BN=128 BK=64, 8 waves 4Mx2N, acc[4][4], 256-block
// grids, XCD maps) with a faithful m201-style pipeline: TRIPLE-buffered LDS
// (144KB), stage 2 K-tiles ahead, 2 uniform phases/tile, ds_reads issued
// BEFORE the barrier (latency hides under barrier-arrival spread), one
// counted vmcnt(6) per tile (6 loads always in flight), setprio around MFMA.
// Theory: all prior rounds delivered staged bytes at ~10.5 B/cy/CU (bursty
// DMA issue); m201's uniform issue sustains ~19 B/cy -> ~2x gemm speedup.

typedef float  f32x4  __attribute__((ext_vector_type(4)));
typedef __bf16 bf16x8 __attribute__((ext_vector_type(8)));

__device__ __forceinline__ unsigned short f2bf(float f) {
  union { float f; unsigned int u; } c; c.f = f;
  unsigned int u = c.u;
  u += 0x7FFFu + ((u >> 16) & 1u);   // RNE; inputs finite
  return (unsigned short)(u >> 16);
}

__device__ __forceinline__ void async_cp16(const void* g, void* l) {
  __builtin_amdgcn_global_load_lds(
      (const __attribute__((address_space(1))) unsigned int*)g,
      (__attribute__((address_space(3))) unsigned int*)l, 16, 0, 0);
}

__device__ __forceinline__ void bar() { asm volatile("s_barrier" ::: "memory"); }
#define VMCNT(n) asm volatile("s_waitcnt vmcnt(" #n ")" ::: "memory")

// ---------------- fused pre-pass (unchanged) ----------------

__global__ __launch_bounds__(256) void k_prep(
    const float4* __restrict__ y4, const float4* __restrict__ a4,
    ushort4* __restrict__ yb, ushort4* __restrict__ ab,
    const float* __restrict__ W, unsigned short* __restrict__ Wt)
{
  __shared__ float t[64][65];
  const int bid = blockIdx.x;
  if (bid < 16384) {
    const int i = bid * 256 + threadIdx.x;
    const bool isY = i < 2097152;
    const float4 v = isY ? y4[i] : a4[i - 2097152];
    ushort4 p;
    p.x = f2bf(v.x); p.y = f2bf(v.y); p.z = f2bf(v.z); p.w = f2bf(v.w);
    if (isY) yb[i] = p; else ab[i - 2097152] = p;
  } else {
    const int id = bid - 16384;
    const int n0 = (id & 15) * 64, k0 = (id >> 4) * 64;
    const int tx = threadIdx.x & 63, ty = threadIdx.x >> 6;
#pragma unroll
    for (int r = ty; r < 64; r += 4)
      t[r][tx] = W[(size_t)(k0 + r) * 1024 + n0 + tx];
    __syncthreads();
#pragma unroll
    for (int r = ty; r < 64; r += 4)
      Wt[(size_t)(n0 + r) * 1024 + k0 + tx] = f2bf(t[tx][r]);
  }
}

// ---------------- GEMM pieces: 256x128 tile, BK=64, 8 waves ----------------
// LDS buffer (48KB each, x3): A[256][64] bf16 at +0, B[128][64] at +16384.
// LDS row = 128B = 8 chunks of 16B; physical chunk = (logical + row) & 7.
// Staging applies the inverse permutation on the global k-column; all staging
// row bases are multiples of 8 so the mod-8 algebra is unchanged (proven R3+).
// Units (each 16KB, 2 loads/thread): A-half c = rows [c*128, c*128+128); B.

__device__ __forceinline__ void stageA(
    const unsigned short* __restrict__ A, int sA, int m0, int k0, int c,
    unsigned short* la, int wave, int rg, int colo)
{
#pragma unroll
  for (int s = 0; s < 2; ++s) {
    const int t = wave * 2 + s;                        // 0..15
    const int row0 = c * 128 + t * 8;
    async_cp16(A + (size_t)(m0 + row0 + rg) * sA + k0 + colo, la + row0 * 64);
  }
}

__device__ __forceinline__ void stageB(
    const unsigned short* __restrict__ Bt, int sB, int n0, int k0,
    unsigned short* lb, int wave, int rg, int colo)
{
#pragma unroll
  for (int s = 0; s < 2; ++s) {
    const int t = wave * 2 + s;                        // 0..15
    const int row0 = t * 8;
    async_cp16(Bt + (size_t)(n0 + row0 + rg) * sB + k0 + colo, lb + row0 * 64);
  }
}

__device__ __forceinline__ void readA(
    const unsigned short* la, bf16x8 af[2][4], int wm, int quad, int l16)
{
#pragma unroll
  for (int h = 0; h < 2; ++h)
#pragma unroll
    for (int i = 0; i < 4; ++i) {
      const int r = wm + i * 16 + l16;
      af[h][i] = *(const bf16x8*)(la + r * 64 + ((h * 4 + quad + r) & 7) * 8);
    }
}

__device__ __forceinline__ void readB(
    const unsigned short* lb, bf16x8 bfr[2][2], int wn, int nh, int quad, int l16)
{
#pragma unroll
  for (int h = 0; h < 2; ++h)
#pragma unroll
    for (int j = 0; j < 2; ++j) {
      const int r = wn + nh * 32 + j * 16 + l16;
      bfr[h][j] = *(const bf16x8*)(lb + r * 64 + ((h * 4 + quad + r) & 7) * 8);
    }
}

__device__ __forceinline__ void phase16(
    bf16x8 af[2][4], bf16x8 bfr[2][2], f32x4 acc[4][4], int nh)
{
  __builtin_amdgcn_s_setprio(1);
#pragma unroll
  for (int h = 0; h < 2; ++h)
#pragma unroll
    for (int i = 0; i < 4; ++i)
#pragma unroll
      for (int j = 0; j < 2; ++j)
        acc[i][nh * 2 + j] = __builtin_amdgcn_mfma_f32_16x16x32_bf16(
            af[h][i], bfr[h][j], acc[i][nh * 2 + j], 0, 0, 0);
  __builtin_amdgcn_s_setprio(0);
}

// 16 K-tiles, TRIPLE-buffered, staged 2 tiles ahead. Per tile T:
//  alpha: issue stage A0(T+2); ds_read A(T)x8 + B0(T)x4; BAR;
//         16 MFMA (acc cols 0-1); BAR.
//  beta:  issue stage A1(T+2) + B(T+2); ds_read B1(T)x4;
//         VMCNT(6) [drain T+1's 6 units, keep T+2's 6]; BAR;
//         16 MFMA (acc cols 2-3); BAR.
// WAR-safe: stage target for T+2 (= buffer of T-1) was fully consumed at
// iteration T-1 and all its readers passed a barrier before this issue.
__device__ __forceinline__ void gemm_3buf(
    const unsigned short* __restrict__ A,  int sA,
    const unsigned short* __restrict__ Bt, int sB,
    int m0, int n0, f32x4 acc[4][4], unsigned short* lsm, int tid)
{
  const int lane = tid & 63, wave = tid >> 6;
  const int wm = (wave >> 1) * 64, wn = (wave & 1) * 64;
  const int quad = lane >> 4, l16 = lane & 15;
  const int rg = lane >> 3;
  const int colo = (((lane & 7) - rg) & 7) * 8;   // inverse-swizzled k-offset

  unsigned short* cur = lsm;
  unsigned short* nxt = lsm + 24576;
  unsigned short* stg = lsm + 49152;

  bf16x8 af[2][4], bfr[2][2];

  // prologue: stage tiles 0 and 1 fully (6 units); drain tile 0 only
  stageA(A, sA, m0, 0, 0, cur, wave, rg, colo);
  stageA(A, sA, m0, 0, 1, cur, wave, rg, colo);
  stageB(Bt, sB, n0, 0, cur + 16384, wave, rg, colo);
  stageA(A, sA, m0, 64, 0, nxt, wave, rg, colo);
  stageA(A, sA, m0, 64, 1, nxt, wave, rg, colo);
  stageB(Bt, sB, n0, 64, nxt + 16384, wave, rg, colo);
  VMCNT(6);
  bar();

#pragma unroll 1
  for (int T = 0; T < 16; ++T) {
    const int nk = (T + 2) * 64;

    // ---- phase alpha: acc cols 0-1 ----
    if (T < 14) stageA(A, sA, m0, nk, 0, stg, wave, rg, colo);
    readA(cur, af, wm, quad, l16);
    readB(cur + 16384, bfr, wn, 0, quad, l16);
    bar();
    phase16(af, bfr, acc, 0);
    bar();

    // ---- phase beta: acc cols 2-3 ----
    if (T < 14) {
      stageA(A, sA, m0, nk, 1, stg, wave, rg, colo);
      stageB(Bt, sB, n0, nk, stg + 16384, wave, rg, colo);
    }
    readB(cur + 16384, bfr, wn, 1, quad, l16);
    if (T < 14)       { VMCNT(6); }
    else if (T == 14) { VMCNT(0); }
    bar();
    phase16(af, bfr, acc, 1);
    bar();

    // rotate buffers: cur <- nxt <- stg <- cur
    unsigned short* tmp = cur; cur = nxt; nxt = stg; stg = tmp;
  }
}

__device__ __forceinline__ void zero_acc(f32x4 acc[4][4]) {
#pragma unroll
  for (int i = 0; i < 4; ++i)
#pragma unroll
    for (int j = 0; j < 4; ++j)
#pragma unroll
      for (int r = 0; r < 4; ++r) acc[i][j][r] = 0.0f;
}

// ---------------- GEMM1: Sup2[d][b*1024+n] = (y@W)^T ----------------
// 256 blocks; xcd = bid&7 owns 8 n-tiles per m-row -> per-XCD working set
// Wt (2MB) + ybf n-slice (2MB) = one L2.

__global__ __launch_bounds__(512, 2) void k_gemm1(
    const unsigned short* __restrict__ Wt,    // [1024][1024]
    const unsigned short* __restrict__ Ybf,   // [8192][1024]
    unsigned short* __restrict__ Sup2)        // [1024][8192]
{
  __shared__ __align__(16) unsigned short lsm[73728];  // 144 KB
  const int tid = threadIdx.x;
  const int xcd = blockIdx.x & 7, slot = blockIdx.x >> 3;  // slot 0..31
  const int m0 = (slot >> 3) * 256;                        // 4 m-tiles
  const int n0 = (xcd * 8 + (slot & 7)) * 128;             // 64 n-tiles

  f32x4 acc[4][4];
  zero_acc(acc);
  gemm_3buf(Wt, 1024, Ybf, 1024, m0, n0, acc, lsm, tid);

  const int lane = tid & 63, wave = tid >> 6;
  const int wm = (wave >> 1) * 64, wn = (wave & 1) * 64;
  const int quad = lane >> 4, l16 = lane & 15;
#pragma unroll
  for (int mi = 0; mi < 4; ++mi) {
    const int mb = m0 + wm + mi * 16 + quad * 4;
#pragma unroll
    for (int r = 0; r < 4; ++r) {
      unsigned short* row = Sup2 + ((size_t)(mb + r) << 13);
#pragma unroll
      for (int nj = 0; nj < 4; ++nj)
        row[n0 + wn + nj * 16 + l16] = f2bf(acc[mi][nj][r]);
    }
  }
}

// ------- GEMM2: out = relu(adj@support / rowsum + bias + x) -------
// 256 blocks; xcd = bid&7 owns batch b -> adjbf[b] (2MB) + sup2 b-slice (2MB)
// = one L2.

__global__ __launch_bounds__(512, 2) void k_gemm2(
    const unsigned short* __restrict__ AdjBf, // [8][1024][1024]
    const unsigned short* __restrict__ Sup2,  // [1024][8192]
    const float* __restrict__ x,
    const float* __restrict__ sumrow,         // [8][1024]
    const float* __restrict__ bias,           // [1024]
    float* __restrict__ out)
{
  __shared__ __align__(16) unsigned short lsm[73728];  // 144 KB
  const int tid = threadIdx.x;
  const int b = blockIdx.x & 7, slot = blockIdx.x >> 3;  // slot 0..31
  const int m0 = (slot >> 3) * 256, n0 = (slot & 7) * 128;

  f32x4 acc[4][4];
  zero_acc(acc);
  gemm_3buf(AdjBf + ((size_t)b << 20), 1024,
            Sup2 + ((size_t)b << 10), 8192,
            m0, n0, acc, lsm, tid);

  const float* xb = x   + ((size_t)b << 20);
  float*       ob = out + ((size_t)b << 20);
  const float* sr = sumrow + ((size_t)b << 10);
  const int lane = tid & 63, wave = tid >> 6;
  const int wm = (wave >> 1) * 64, wn = (wave & 1) * 64;
  const int quad = lane >> 4, l16 = lane & 15;

  float bv[4];
#pragma unroll
  for (int nj = 0; nj < 4; ++nj) bv[nj] = bias[n0 + wn + nj * 16 + l16];

#pragma unroll
  for (int mi = 0; mi < 4; ++mi) {
    const int mb = m0 + wm + mi * 16 + quad * 4;
#pragma unroll
    for (int r = 0; r < 4; ++r) {
      const int m = mb + r;
      const float inv = 1.0f / sr[m];
#pragma unroll
      for (int nj = 0; nj < 4; ++nj) {
        const int n = n0 + wn + nj * 16 + l16;
        const size_t idx = (((size_t)m) << 10) + n;
        float v = acc[mi][nj][r] * inv + bv[nj] + xb[idx];
        ob[idx] = fmaxf(v, 0.0f);
      }
    }
  }
}

// ---------------- launcher ----------------

extern "C" void kernel_launch(void* const* d_in, const int* in_sizes, int n_in,
                              void* d_out, int out_size, void* d_ws, size_t ws_size,
                              hipStream_t stream) {
  const float* x      = (const float*)d_in[0];
  const float* y      = (const float*)d_in[1];
  const float* adj    = (const float*)d_in[2];
  const float* sumrow = (const float*)d_in[3];
  const float* W      = (const float*)d_in[4];
  const float* bias   = (const float*)d_in[5];
  float* out = (float*)d_out;

  char* ws = (char*)d_ws;
  unsigned short* ybf   = (unsigned short*)(ws);                       // 16 MB
  unsigned short* adjbf = (unsigned short*)(ws + ((size_t)16 << 20));  // 16 MB
  unsigned short* wt    = (unsigned short*)(ws + ((size_t)32 << 20));  //  2 MB
  unsigned short* sup2  = (unsigned short*)(ws + ((size_t)34 << 20));  // 16 MB

  k_prep<<<dim3(16640), dim3(256), 0, stream>>>(
      (const float4*)y, (const float4*)adj, (ushort4*)ybf, (ushort4*)adjbf, W, wt);
  k_gemm1<<<dim3(256), dim3(512), 0, stream>>>(wt, ybf, sup2);
  k_gemm2<<<dim3(256), dim3(512), 0, stream>>>(adjbf, sup2, x, sumrow, bias, out);
}